// Round 4
// baseline (482.822 us; speedup 1.0000x reference)
//
#include <hip/hip_runtime.h>
#include <hip/hip_bf16.h>

#define TQn 1024
#define NB  16
#define DIM 1024
#define BM  128
#define BN  128
#define BK  32
#define STR 40
#define VSTR 132

typedef __attribute__((ext_vector_type(4))) float f32x4;
typedef __attribute__((ext_vector_type(8))) short s16x8;
typedef __attribute__((ext_vector_type(4))) short s16x4;

__device__ __forceinline__ short f2bf(float f){
  union { float f; unsigned u; } v; v.f = f;
  unsigned r = v.u + 0x7fffu + ((v.u >> 16) & 1u);  // RNE
  return (short)(r >> 16);
}
__device__ __forceinline__ float bf2f(short h){
  union { unsigned u; float f; } v; v.u = ((unsigned)(unsigned short)h) << 16;
  return v.f;
}

__device__ __forceinline__ void gload16(const short* g, short* l){
#if __has_builtin(__builtin_amdgcn_global_load_lds)
  __builtin_amdgcn_global_load_lds(
      (const __attribute__((address_space(1))) unsigned int*)(const void*)g,
      (__attribute__((address_space(3))) unsigned int*)(void*)l, 16, 0, 0);
#else
  *reinterpret_cast<s16x8*>(l) = *reinterpret_cast<const s16x8*>(g);
#endif
}

// ---------------- fast path ----------------

// split fp32 -> bf16 hi/lo planes (elementwise, memory-bound)
__global__ __launch_bounds__(256) void k0_split(const float* __restrict__ in,
                                                short* __restrict__ hi,
                                                short* __restrict__ lo){
  const size_t i = ((size_t)blockIdx.x * 256 + threadIdx.x) * 4;
  f32x4 v = *reinterpret_cast<const f32x4*>(in + i);
  s16x4 h, l;
  #pragma unroll
  for (int j = 0; j < 4; ++j){ h[j] = f2bf(v[j]); l[j] = f2bf(v[j] - bf2f(h[j])); }
  *reinterpret_cast<s16x4*>(hi + i) = h;
  *reinterpret_cast<s16x4*>(lo + i) = l;
}

// values [b][s][v] fp32 -> vT [b][v][s] bf16 (tiled transpose)
__global__ __launch_bounds__(256) void k0_vtrans(const float* __restrict__ vals,
                                                 short* __restrict__ vT){
  __shared__ short T[64 * 72];
  const int t = threadIdx.x;
  const int v0 = blockIdx.x * 64, s0 = blockIdx.y * 64, b = blockIdx.z;
  const int r16 = t >> 4, c4 = (t & 15) * 4;
  #pragma unroll
  for (int i = 0; i < 4; ++i){
    const int sl = i * 16 + r16;
    f32x4 v = *reinterpret_cast<const f32x4*>(vals + ((size_t)b * TQn + s0 + sl) * DIM + v0 + c4);
    #pragma unroll
    for (int j = 0; j < 4; ++j) T[(c4 + j) * 72 + sl] = f2bf(v[j]);
  }
  __syncthreads();
  #pragma unroll
  for (int i = 0; i < 4; ++i){
    const int vl = i * 16 + r16;
    s16x4 o = *reinterpret_cast<const s16x4*>(&T[vl * 72 + c4]);
    *reinterpret_cast<s16x4*>(vT + ((size_t)b * DIM + v0 + vl) * TQn + s0 + c4) = o;
  }
}

// unified bf16 A*B^T GEMM, 128x128 tile, BK=64, fragment-major LDS, global_load_lds staging.
// CH=3: acc += Ah*Bh + Al*Bh + Ah*Bl.  EPI=0: fp32 C.  EPI=1: bf16 hi/lo C planes.
// elem offsets: A row m: (m*ARS + bz*ABO)*1024 ; C: (crow + bz*CBO)*1024 + col
template<int CH, int EPI>
__global__ __launch_bounds__(256) void gemm_bt(
    const short* __restrict__ Ah, const short* __restrict__ Al,
    const short* __restrict__ Bh, const short* __restrict__ Bl,
    float* __restrict__ C, short* __restrict__ Ch, short* __restrict__ Cl,
    int ARS, int ABO, int BRS, int BBO, int CBO)
{
  constexpr int APL = (CH == 3) ? 2 : 1;
  constexpr int CPW = APL * 8;           // staging chunks per wave
  constexpr int BHB = APL * 8192;        // B-planes LDS base (shorts)
  __shared__ __align__(16) short lds[2 * APL * 8192];
  const int tid = threadIdx.x;
  const int lane = tid & 63, wid = tid >> 6;
  const int cl = lane & 15, kg = lane >> 4;
  const int lane8 = lane * 8;
  const int bx = blockIdx.x, by = blockIdx.y, bz = blockIdx.z;
  const int wmf = (wid >> 1) * 4, wnf = (wid & 1) * 4;

  // staging: each wave owns one (CH=3) or half of one (CH=1) plane's 16KB tile
  const bool isA = (wid < 2);
  const short* P;
  if (CH == 3) P = (wid == 0) ? Ah : (wid == 1) ? Al : (wid == 2) ? Bh : Bl;
  else         P = (wid < 2) ? Ah : Bh;
  const int RS = isA ? ARS : BRS, BO = isA ? ABO : BBO;
  const int blk = (isA ? by : bx) * 128;
  int offs[CPW];
  #pragma unroll
  for (int c = 0; c < CPW; ++c){
    const int frag = (CH == 3) ? c : ((wid & 1) * 8 + c);
    const int row = blk + (frag >> 1) * 16 + cl;
    offs[c] = (row * RS + bz * BO) * 1024 + (frag & 1) * 32 + kg * 8;
  }
  const int ldsw = ((CH == 3) ? wid * 8192 : ((wid >> 1) * 8192 + (wid & 1) * 4096)) + lane8;

  f32x4 acc[4][4] = {};
  for (int k0 = 0; k0 < 1024; k0 += 64){
    #pragma unroll
    for (int c = 0; c < CPW; ++c)
      gload16(P + (size_t)(offs[c] + k0), &lds[ldsw + c * 512]);
    __syncthreads();           // drains vmcnt -> LDS tile ready
    #pragma unroll
    for (int kk = 0; kk < 2; ++kk){
      s16x8 ahv[4], bhv[4], alv[4], blv[4];
      #pragma unroll
      for (int i = 0; i < 4; ++i){
        ahv[i] = *reinterpret_cast<const s16x8*>(&lds[((wmf + i) * 2 + kk) * 512 + lane8]);
        bhv[i] = *reinterpret_cast<const s16x8*>(&lds[BHB + ((wnf + i) * 2 + kk) * 512 + lane8]);
        if (CH == 3){
          alv[i] = *reinterpret_cast<const s16x8*>(&lds[8192 + ((wmf + i) * 2 + kk) * 512 + lane8]);
          blv[i] = *reinterpret_cast<const s16x8*>(&lds[BHB + 8192 + ((wnf + i) * 2 + kk) * 512 + lane8]);
        }
      }
      #pragma unroll
      for (int m = 0; m < 4; ++m)
        #pragma unroll
        for (int n = 0; n < 4; ++n){
          acc[m][n] = __builtin_amdgcn_mfma_f32_16x16x32_bf16(ahv[m], bhv[n], acc[m][n], 0, 0, 0);
          if (CH == 3){
            acc[m][n] = __builtin_amdgcn_mfma_f32_16x16x32_bf16(alv[m], bhv[n], acc[m][n], 0, 0, 0);
            acc[m][n] = __builtin_amdgcn_mfma_f32_16x16x32_bf16(ahv[m], blv[n], acc[m][n], 0, 0, 0);
          }
        }
    }
    __syncthreads();           // protect LDS before next stage
  }
  #pragma unroll
  for (int m = 0; m < 4; ++m){
    const int crow0 = by * 128 + wmf * 16 + m * 16 + kg * 4;
    #pragma unroll
    for (int n = 0; n < 4; ++n){
      const int col = bx * 128 + wnf * 16 + n * 16 + cl;
      #pragma unroll
      for (int j = 0; j < 4; ++j){
        const size_t off = ((size_t)(crow0 + j) + (size_t)bz * CBO) * 1024 + col;
        if (EPI == 0) C[off] = acc[m][n][j];
        else {
          const float v = acc[m][n][j];
          const short h = f2bf(v);
          Ch[off] = h; Cl[off] = f2bf(v - bf2f(h));
        }
      }
    }
  }
}

// K3: in-place row softmax of (logits + mask[b][s]); optional bf16 copy for K4
__global__ __launch_bounds__(256) void k3_softmax(float* __restrict__ logits,
                                                  const float* __restrict__ mask,
                                                  short* __restrict__ sbf){
  const int row = blockIdx.x;       // b*TQ + t
  const int b = row >> 10;
  const int tid = threadIdx.x;
  float* p = logits + (size_t)row * DIM;
  f32x4 v  = *reinterpret_cast<const f32x4*>(p + tid * 4);
  f32x4 mk = *reinterpret_cast<const f32x4*>(mask + (size_t)b * DIM + tid * 4);
  v = v + mk;
  float mx = fmaxf(fmaxf(v[0], v[1]), fmaxf(v[2], v[3]));
  #pragma unroll
  for (int off = 32; off; off >>= 1) mx = fmaxf(mx, __shfl_xor(mx, off));
  __shared__ float red[8];
  const int lane = tid & 63, wid = tid >> 6;
  if (lane == 0) red[wid] = mx;
  __syncthreads();
  mx = fmaxf(fmaxf(red[0], red[1]), fmaxf(red[2], red[3]));
  f32x4 e;
  #pragma unroll
  for (int j = 0; j < 4; ++j) e[j] = __expf(v[j] - mx);
  float s = e[0] + e[1] + e[2] + e[3];
  #pragma unroll
  for (int off = 32; off; off >>= 1) s += __shfl_xor(s, off);
  if (lane == 0) red[4 + wid] = s;
  __syncthreads();
  s = red[4] + red[5] + red[6] + red[7];
  const float inv = 1.0f / s;
  f32x4 o;
  s16x4 ob;
  #pragma unroll
  for (int j = 0; j < 4; ++j){ o[j] = e[j] * inv; ob[j] = f2bf(o[j]); }
  *reinterpret_cast<f32x4*>(p + tid * 4) = o;
  if (sbf) *reinterpret_cast<s16x4*>(sbf + (size_t)row * DIM + tid * 4) = ob;
}

// ---------------- fallback (round-3 passing) kernels ----------------

__global__ __launch_bounds__(256) void k1_qp(const float* __restrict__ A,
                                             const float* __restrict__ Wm,
                                             float* __restrict__ C){
  __shared__ __align__(16) short Ah[BM * STR];
  __shared__ __align__(16) short Al[BM * STR];
  __shared__ __align__(16) short Bh[BN * STR];
  __shared__ __align__(16) short Bl[BN * STR];
  const int tid = threadIdx.x;
  const int m0 = blockIdx.y * BM, n0 = blockIdx.x * BN;
  const int lane = tid & 63, wid = tid >> 6;
  const int wm = (wid >> 1) * 64, wn = (wid & 1) * 64;
  const int cl = lane & 15, kg = lane >> 4;
  const int rr = tid >> 3, f4 = (tid & 7) * 4;
  f32x4 acc[4][4] = {};
  for (int k0 = 0; k0 < DIM; k0 += BK){
    #pragma unroll
    for (int i = 0; i < 4; ++i){
      const int r = rr + i * 32;
      f32x4 va = *reinterpret_cast<const f32x4*>(A  + (size_t)(m0 + r) * DIM + k0 + f4);
      f32x4 vb = *reinterpret_cast<const f32x4*>(Wm + (size_t)(n0 + r) * DIM + k0 + f4);
      s16x4 ha, la, hb, lb;
      #pragma unroll
      for (int j = 0; j < 4; ++j){
        ha[j] = f2bf(va[j]); la[j] = f2bf(va[j] - bf2f(ha[j]));
        hb[j] = f2bf(vb[j]); lb[j] = f2bf(vb[j] - bf2f(hb[j]));
      }
      *reinterpret_cast<s16x4*>(&Ah[r * STR + f4]) = ha;
      *reinterpret_cast<s16x4*>(&Al[r * STR + f4]) = la;
      *reinterpret_cast<s16x4*>(&Bh[r * STR + f4]) = hb;
      *reinterpret_cast<s16x4*>(&Bl[r * STR + f4]) = lb;
    }
    __syncthreads();
    s16x8 ah[4], al8[4], bh8[4], bl8[4];
    #pragma unroll
    for (int m = 0; m < 4; ++m){
      ah[m]  = *reinterpret_cast<const s16x8*>(&Ah[(wm + m * 16 + cl) * STR + kg * 8]);
      al8[m] = *reinterpret_cast<const s16x8*>(&Al[(wm + m * 16 + cl) * STR + kg * 8]);
    }
    #pragma unroll
    for (int n = 0; n < 4; ++n){
      bh8[n] = *reinterpret_cast<const s16x8*>(&Bh[(wn + n * 16 + cl) * STR + kg * 8]);
      bl8[n] = *reinterpret_cast<const s16x8*>(&Bl[(wn + n * 16 + cl) * STR + kg * 8]);
    }
    #pragma unroll
    for (int m = 0; m < 4; ++m)
      #pragma unroll
      for (int n = 0; n < 4; ++n){
        acc[m][n] = __builtin_amdgcn_mfma_f32_16x16x32_bf16(ah[m],  bh8[n], acc[m][n], 0, 0, 0);
        acc[m][n] = __builtin_amdgcn_mfma_f32_16x16x32_bf16(al8[m], bh8[n], acc[m][n], 0, 0, 0);
        acc[m][n] = __builtin_amdgcn_mfma_f32_16x16x32_bf16(ah[m],  bl8[n], acc[m][n], 0, 0, 0);
      }
    __syncthreads();
  }
  #pragma unroll
  for (int m = 0; m < 4; ++m){
    const int row = m0 + wm + m * 16 + kg * 4;
    #pragma unroll
    for (int n = 0; n < 4; ++n){
      const int col = n0 + wn + n * 16 + cl;
      #pragma unroll
      for (int j = 0; j < 4; ++j)
        C[(size_t)(row + j) * DIM + col] = acc[m][n][j];
    }
  }
}

__global__ __launch_bounds__(256) void k2_logits(const float* __restrict__ qp,
                                                 const float* __restrict__ keys,
                                                 float* __restrict__ out){
  __shared__ __align__(16) short Ah[BM * STR];
  __shared__ __align__(16) short Al[BM * STR];
  __shared__ __align__(16) short Bh[BN * STR];
  __shared__ __align__(16) short Bl[BN * STR];
  const int tid = threadIdx.x;
  const int b = blockIdx.z;
  const int t0 = blockIdx.y * BM, s0 = blockIdx.x * BN;
  const int lane = tid & 63, wid = tid >> 6;
  const int wm = (wid >> 1) * 64, wn = (wid & 1) * 64;
  const int cl = lane & 15, kg = lane >> 4;
  const int rr = tid >> 3, f4 = (tid & 7) * 4;
  f32x4 acc[4][4] = {};
  for (int k0 = 0; k0 < DIM; k0 += BK){
    #pragma unroll
    for (int i = 0; i < 4; ++i){
      const int r = rr + i * 32;
      f32x4 va = *reinterpret_cast<const f32x4*>(qp   + (size_t)((t0 + r) * NB + b) * DIM + k0 + f4);
      f32x4 vb = *reinterpret_cast<const f32x4*>(keys + ((size_t)b * DIM + s0 + r) * DIM + k0 + f4);
      s16x4 ha, la, hb, lb;
      #pragma unroll
      for (int j = 0; j < 4; ++j){
        ha[j] = f2bf(va[j]); la[j] = f2bf(va[j] - bf2f(ha[j]));
        hb[j] = f2bf(vb[j]); lb[j] = f2bf(vb[j] - bf2f(hb[j]));
      }
      *reinterpret_cast<s16x4*>(&Ah[r * STR + f4]) = ha;
      *reinterpret_cast<s16x4*>(&Al[r * STR + f4]) = la;
      *reinterpret_cast<s16x4*>(&Bh[r * STR + f4]) = hb;
      *reinterpret_cast<s16x4*>(&Bl[r * STR + f4]) = lb;
    }
    __syncthreads();
    s16x8 ah[4], al8[4], bh8[4], bl8[4];
    #pragma unroll
    for (int m = 0; m < 4; ++m){
      ah[m]  = *reinterpret_cast<const s16x8*>(&Ah[(wm + m * 16 + cl) * STR + kg * 8]);
      al8[m] = *reinterpret_cast<const s16x8*>(&Al[(wm + m * 16 + cl) * STR + kg * 8]);
    }
    #pragma unroll
    for (int n = 0; n < 4; ++n){
      bh8[n] = *reinterpret_cast<const s16x8*>(&Bh[(wn + n * 16 + cl) * STR + kg * 8]);
      bl8[n] = *reinterpret_cast<const s16x8*>(&Bl[(wn + n * 16 + cl) * STR + kg * 8]);
    }
    #pragma unroll
    for (int m = 0; m < 4; ++m)
      #pragma unroll
      for (int n = 0; n < 4; ++n){
        acc[m][n] = __builtin_amdgcn_mfma_f32_16x16x32_bf16(ah[m],  bh8[n], acc[m][n], 0, 0, 0);
        acc[m][n] = __builtin_amdgcn_mfma_f32_16x16x32_bf16(al8[m], bh8[n], acc[m][n], 0, 0, 0);
        acc[m][n] = __builtin_amdgcn_mfma_f32_16x16x32_bf16(ah[m],  bl8[n], acc[m][n], 0, 0, 0);
      }
    __syncthreads();
  }
  #pragma unroll
  for (int m = 0; m < 4; ++m){
    const int trow = t0 + wm + m * 16 + kg * 4;
    #pragma unroll
    for (int n = 0; n < 4; ++n){
      const int scol = s0 + wn + n * 16 + cl;
      #pragma unroll
      for (int j = 0; j < 4; ++j)
        out[((size_t)b * TQn + trow + j) * DIM + scol] = acc[m][n][j];
    }
  }
}

__global__ __launch_bounds__(256) void k4_ctx(const float* __restrict__ score,
                                              const float* __restrict__ values,
                                              float* __restrict__ ctx){
  __shared__ __align__(16) short As[BM * STR];
  __shared__ __align__(16) float Vs[BK * VSTR];
  const int tid = threadIdx.x;
  const int b = blockIdx.z;
  const int t0 = blockIdx.y * BM, v0 = blockIdx.x * BN;
  const int lane = tid & 63, wid = tid >> 6;
  const int wm = (wid >> 1) * 64, wn = (wid & 1) * 64;
  const int cl = lane & 15, kg = lane >> 4;
  const int rr = tid >> 3, f4 = (tid & 7) * 4;
  const int vr = tid >> 5, vc = tid & 31;
  f32x4 acc[4][4] = {};
  for (int k0 = 0; k0 < DIM; k0 += BK){
    #pragma unroll
    for (int i = 0; i < 4; ++i){
      const int r = rr + i * 32;
      f32x4 va = *reinterpret_cast<const f32x4*>(score + ((size_t)b * TQn + t0 + r) * DIM + k0 + f4);
      s16x4 ha;
      #pragma unroll
      for (int j = 0; j < 4; ++j) ha[j] = f2bf(va[j]);
      *reinterpret_cast<s16x4*>(&As[r * STR + f4]) = ha;
      const int vrow = vr + i * 8;
      f32x4 vv = *reinterpret_cast<const f32x4*>(values + ((size_t)b * DIM + k0 + vrow) * DIM + v0 + vc * 4);
      const int cb = vc ^ (((vrow >> 3) & 1) << 2);
      *reinterpret_cast<f32x4*>(&Vs[vrow * VSTR + cb * 4]) = vv;
    }
    __syncthreads();
    s16x8 af[4], bfr[4];
    #pragma unroll
    for (int m = 0; m < 4; ++m)
      af[m] = *reinterpret_cast<const s16x8*>(&As[(wm + m * 16 + cl) * STR + kg * 8]);
    #pragma unroll
    for (int n = 0; n < 4; ++n){
      const int colb = wn + n * 16 + cl;
      const int cb = (colb >> 2) ^ ((kg & 1) << 2);
      #pragma unroll
      for (int j = 0; j < 8; ++j){
        const int rowv = kg * 8 + j;
        bfr[n][j] = f2bf(Vs[rowv * VSTR + cb * 4 + (colb & 3)]);
      }
    }
    #pragma unroll
    for (int m = 0; m < 4; ++m)
      #pragma unroll
      for (int n = 0; n < 4; ++n)
        acc[m][n] = __builtin_amdgcn_mfma_f32_16x16x32_bf16(af[m], bfr[n], acc[m][n], 0, 0, 0);
    __syncthreads();
  }
  #pragma unroll
  for (int m = 0; m < 4; ++m){
    const int trow = t0 + wm + m * 16 + kg * 4;
    #pragma unroll
    for (int n = 0; n < 4; ++n){
      const int vcol = v0 + wn + n * 16 + cl;
      #pragma unroll
      for (int j = 0; j < 4; ++j)
        ctx[((size_t)b * TQn + trow + j) * DIM + vcol] = acc[m][n][j];
    }
  }
}

extern "C" void kernel_launch(void* const* d_in, const int* in_sizes, int n_in,
                              void* d_out, int out_size, void* d_ws, size_t ws_size,
                              hipStream_t stream){
  (void)in_sizes; (void)n_in; (void)out_size;
  const float* query  = (const float*)d_in[0];  // [1024][16][1024] == m-major [16384][1024]
  const float* keys   = (const float*)d_in[1];  // [16][1024][1024]
  const float* values = (const float*)d_in[2];  // [16][1024][1024]
  const float* mask   = (const float*)d_in[3];  // [16][1024]
  const float* Wm     = (const float*)d_in[4];  // [1024][1024]
  float* score = (float*)d_out;                              // [16][1024][1024]
  float* ctx   = score + (size_t)NB * TQn * DIM;             // qp-plane scratch then real ctx
  dim3 blk(256, 1, 1);

  const size_t M16 = (size_t)16 * 1024 * 1024;   // 16M shorts
  const size_t M1  = (size_t)1024 * 1024;
  const size_t need = (4 * M16 + 2 * M1 + 2 * M16) * 2;   // 196 MB
  if (ws_size >= need){
    short* w  = (short*)d_ws;
    short* qh = w;                 // query hi
    short* ql = qh + M16;
    short* kh = ql + M16;          // keys hi
    short* kl = kh + M16;
    short* wh = kl + M16;          // W hi
    short* wl = wh + M1;
    short* vT = wl + M1;           // values^T bf16 [b][v][s]
    short* sb = vT + M16;          // score bf16
    short* qph = (short*)ctx;      // qp hi plane (m-major [16384][1024])
    short* qpl = qph + M16;

    k0_split<<<dim3(16384, 1, 1), blk, 0, stream>>>(query, qh, ql);
    k0_split<<<dim3(16384, 1, 1), blk, 0, stream>>>(keys, kh, kl);
    k0_split<<<dim3(1024, 1, 1), blk, 0, stream>>>(Wm, wh, wl);
    k0_vtrans<<<dim3(16, 16, 16), blk, 0, stream>>>(values, vT);
    // K1: qp = query . W^T  -> bf16 hi/lo planes
    gemm_bt<3, 1><<<dim3(8, 128, 1), blk, 0, stream>>>(qh, ql, wh, wl,
        nullptr, qph, qpl, 1, 0, 1, 0, 0);
    // K2: logits[b][t][s] = qp[t*16+b][:] . keys[b][s][:]
    gemm_bt<3, 0><<<dim3(8, 8, 16), blk, 0, stream>>>(qph, qpl, kh, kl,
        score, nullptr, nullptr, 16, 1, 1, 1024, 1024);
    k3_softmax<<<dim3(NB * TQn, 1, 1), blk, 0, stream>>>(score, mask, sb);
    // K4: ctx[b][t][v] = score[b][t][:] . vT[b][v][:]
    gemm_bt<1, 0><<<dim3(8, 8, 16), blk, 0, stream>>>(sb, nullptr, vT, nullptr,
        ctx, nullptr, nullptr, 1, 1024, 1, 1024, 1024);
  } else {
    k1_qp<<<dim3(DIM / BN, (TQn * NB) / BM, 1), blk, 0, stream>>>(query, Wm, ctx);
    k2_logits<<<dim3(DIM / BN, TQn / BM, NB), blk, 0, stream>>>(ctx, keys, score);
    k3_softmax<<<dim3(NB * TQn, 1, 1), blk, 0, stream>>>(score, mask, nullptr);
    k4_ctx<<<dim3(DIM / BN, TQn / BM, NB), blk, 0, stream>>>(score, values, ctx);
  }
}

// Round 5
// 398.437 us; speedup vs baseline: 1.2118x; 1.2118x over previous
//
#include <hip/hip_runtime.h>
#include <hip/hip_bf16.h>

#define TQn 1024
#define NB  16
#define DIM 1024
#define BM  128
#define BN  128
#define BK  32
#define STR 40
#define VSTR 132

typedef __attribute__((ext_vector_type(4))) float f32x4;
typedef __attribute__((ext_vector_type(8))) short s16x8;
typedef __attribute__((ext_vector_type(4))) short s16x4;

__device__ __forceinline__ short f2bf(float f){
  union { float f; unsigned u; } v; v.f = f;
  unsigned r = v.u + 0x7fffu + ((v.u >> 16) & 1u);  // RNE
  return (short)(r >> 16);
}
__device__ __forceinline__ float bf2f(short h){
  union { unsigned u; float f; } v; v.u = ((unsigned)(unsigned short)h) << 16;
  return v.f;
}

__device__ __forceinline__ void gload16(const short* g, short* l){
#if __has_builtin(__builtin_amdgcn_global_load_lds)
  __builtin_amdgcn_global_load_lds(
      (const __attribute__((address_space(1))) unsigned int*)(const void*)g,
      (__attribute__((address_space(3))) unsigned int*)(void*)l, 16, 0, 0);
#else
  *reinterpret_cast<s16x8*>(l) = *reinterpret_cast<const s16x8*>(g);
#endif
}

// ---------------- fast path ----------------

// split fp32 -> bf16 hi/lo planes (elementwise, memory-bound)
__global__ __launch_bounds__(256) void k0_split(const float* __restrict__ in,
                                                short* __restrict__ hi,
                                                short* __restrict__ lo){
  const size_t i = ((size_t)blockIdx.x * 256 + threadIdx.x) * 4;
  f32x4 v = *reinterpret_cast<const f32x4*>(in + i);
  s16x4 h, l;
  #pragma unroll
  for (int j = 0; j < 4; ++j){ h[j] = f2bf(v[j]); l[j] = f2bf(v[j] - bf2f(h[j])); }
  *reinterpret_cast<s16x4*>(hi + i) = h;
  *reinterpret_cast<s16x4*>(lo + i) = l;
}

// values [b][s][v] fp32 -> vT [b][v][s] bf16 (tiled transpose)
__global__ __launch_bounds__(256) void k0_vtrans(const float* __restrict__ vals,
                                                 short* __restrict__ vT){
  __shared__ short T[64 * 72];
  const int t = threadIdx.x;
  const int v0 = blockIdx.x * 64, s0 = blockIdx.y * 64, b = blockIdx.z;
  const int r16 = t >> 4, c4 = (t & 15) * 4;
  #pragma unroll
  for (int i = 0; i < 4; ++i){
    const int sl = i * 16 + r16;
    f32x4 v = *reinterpret_cast<const f32x4*>(vals + ((size_t)b * TQn + s0 + sl) * DIM + v0 + c4);
    #pragma unroll
    for (int j = 0; j < 4; ++j) T[(c4 + j) * 72 + sl] = f2bf(v[j]);
  }
  __syncthreads();
  #pragma unroll
  for (int i = 0; i < 4; ++i){
    const int vl = i * 16 + r16;
    s16x4 o = *reinterpret_cast<const s16x4*>(&T[vl * 72 + c4]);
    *reinterpret_cast<s16x4*>(vT + ((size_t)b * DIM + v0 + vl) * TQn + s0 + c4) = o;
  }
}

// 256x256-tile bf16 A*B^T GEMM, 8 waves, BK=64, double-buffered LDS (128 KB),
// fragment-major layout (conflict-free b128 reads), global_load_lds staging,
// counted-vmcnt pipeline (prefetch stays in flight across barriers).
// CH=3: virtual-K 3x1024 over chains (Ah*Bh + Al*Bh + Ah*Bl), CH=1: plain.
// A row m elem offset: (m*ARS + bz*ABO)*1024 ; C: (crow + bz*CBO)*1024 + col
template<int CH, int EPI>
__global__ __launch_bounds__(512, 2) void gemm256(
    const short* __restrict__ Ah, const short* __restrict__ Al,
    const short* __restrict__ Bh, const short* __restrict__ Bl,
    float* __restrict__ C, short* __restrict__ Ch, short* __restrict__ Cl,
    int ARS, int ABO, int BRS, int BBO, int CBO)
{
  constexpr int NSTEP = (CH == 3) ? 48 : 16;
  __shared__ __align__(16) short lds[2 * 32768];   // 128 KB
  const int tid = threadIdx.x;
  const int lane = tid & 63, w = tid >> 6;
  const int cl = lane & 15, kg = lane >> 4;
  const int bx = blockIdx.x, by = blockIdx.y, bz = blockIdx.z;
  const int wr = w >> 2, wc = w & 3;

  // staging: waves 0-3 own the A tile (32 frags of 16x32), waves 4-7 the B tile.
  const bool isA = (w < 4);
  const int RS = isA ? ARS : BRS, BO = isA ? ABO : BBO;
  const int blk0 = (isA ? by : bx) * 256;
  int offs[8];
  #pragma unroll
  for (int c = 0; c < 8; ++c){
    const int g = (w & 3) * 8 + c;              // frag-chunk within A or B region
    const int row = blk0 + (g >> 1) * 16 + cl;
    offs[c] = (row * RS + bz * BO) * 1024 + (g & 1) * 32 + kg * 8;
  }
  const int sbase = (isA ? 0 : 16384) + (w & 3) * 8 * 512 + lane * 8;

  f32x4 acc[8][4] = {};

  // prologue: stage step 0 (chain 0, k0=0 -> Ah,Bh)
  {
    const short* P = isA ? Ah : Bh;
    #pragma unroll
    for (int c = 0; c < 8; ++c)
      gload16(P + (size_t)offs[c], &lds[sbase + c * 512]);
  }
  for (int t = 0; t < NSTEP; ++t){
    const int buf = (t & 1) * 32768;
    if (t + 1 < NSTEP){
      const int t1 = t + 1;
      const int cc = (CH == 3) ? (t1 % 3) : 0;
      const int k0 = ((CH == 3) ? (t1 / 3) : t1) * 64;
      const short* PA = (CH == 3 && cc == 1) ? Al : Ah;
      const short* PB = (CH == 3 && cc == 2) ? Bl : Bh;
      const short* P = isA ? PA : PB;
      const int nbuf = (t1 & 1) * 32768;
      #pragma unroll
      for (int c = 0; c < 8; ++c)
        gload16(P + (size_t)(offs[c] + k0), &lds[nbuf + sbase + c * 512]);
      asm volatile("s_waitcnt vmcnt(8)" ::: "memory");  // tile t arrived; t+1 in flight
    } else {
      asm volatile("s_waitcnt vmcnt(0)" ::: "memory");
    }
    __builtin_amdgcn_s_barrier();
    __builtin_amdgcn_sched_barrier(0);
    #pragma unroll
    for (int h = 0; h < 2; ++h){
      s16x8 av[8], bv[4];
      #pragma unroll
      for (int n = 0; n < 4; ++n)
        bv[n] = *reinterpret_cast<const s16x8*>(
            &lds[buf + 16384 + (((wc * 4 + n) << 1) + h) * 512 + lane * 8]);
      #pragma unroll
      for (int m = 0; m < 8; ++m)
        av[m] = *reinterpret_cast<const s16x8*>(
            &lds[buf + (((wr * 8 + m) << 1) + h) * 512 + lane * 8]);
      #pragma unroll
      for (int m = 0; m < 8; ++m)
        #pragma unroll
        for (int n = 0; n < 4; ++n)
          acc[m][n] = __builtin_amdgcn_mfma_f32_16x16x32_bf16(av[m], bv[n], acc[m][n], 0, 0, 0);
    }
    __builtin_amdgcn_sched_barrier(0);
    __builtin_amdgcn_s_barrier();          // all waves done reading buf before overwrite
  }
  #pragma unroll
  for (int m = 0; m < 8; ++m){
    const int row0 = by * 256 + wr * 128 + m * 16 + kg * 4;
    #pragma unroll
    for (int n = 0; n < 4; ++n){
      const int col = bx * 256 + wc * 64 + n * 16 + cl;
      #pragma unroll
      for (int j = 0; j < 4; ++j){
        const size_t off = ((size_t)(row0 + j) + (size_t)bz * CBO) * 1024 + col;
        if (EPI == 0) C[off] = acc[m][n][j];
        else {
          const float v = acc[m][n][j];
          const short hh = f2bf(v);
          Ch[off] = hh; Cl[off] = f2bf(v - bf2f(hh));
        }
      }
    }
  }
}

// K3: in-place row softmax of (logits + mask[b][s]); optional bf16 copy for K4
__global__ __launch_bounds__(256) void k3_softmax(float* __restrict__ logits,
                                                  const float* __restrict__ mask,
                                                  short* __restrict__ sbf){
  const int row = blockIdx.x;       // b*TQ + t
  const int b = row >> 10;
  const int tid = threadIdx.x;
  float* p = logits + (size_t)row * DIM;
  f32x4 v  = *reinterpret_cast<const f32x4*>(p + tid * 4);
  f32x4 mk = *reinterpret_cast<const f32x4*>(mask + (size_t)b * DIM + tid * 4);
  v = v + mk;
  float mx = fmaxf(fmaxf(v[0], v[1]), fmaxf(v[2], v[3]));
  #pragma unroll
  for (int off = 32; off; off >>= 1) mx = fmaxf(mx, __shfl_xor(mx, off));
  __shared__ float red[8];
  const int lane = tid & 63, wid = tid >> 6;
  if (lane == 0) red[wid] = mx;
  __syncthreads();
  mx = fmaxf(fmaxf(red[0], red[1]), fmaxf(red[2], red[3]));
  f32x4 e;
  #pragma unroll
  for (int j = 0; j < 4; ++j) e[j] = __expf(v[j] - mx);
  float s = e[0] + e[1] + e[2] + e[3];
  #pragma unroll
  for (int off = 32; off; off >>= 1) s += __shfl_xor(s, off);
  if (lane == 0) red[4 + wid] = s;
  __syncthreads();
  s = red[4] + red[5] + red[6] + red[7];
  const float inv = 1.0f / s;
  f32x4 o;
  s16x4 ob;
  #pragma unroll
  for (int j = 0; j < 4; ++j){ o[j] = e[j] * inv; ob[j] = f2bf(o[j]); }
  *reinterpret_cast<f32x4*>(p + tid * 4) = o;
  if (sbf) *reinterpret_cast<s16x4*>(sbf + (size_t)row * DIM + tid * 4) = ob;
}

// ---------------- fallback (round-3 passing) kernels ----------------

__global__ __launch_bounds__(256) void k1_qp(const float* __restrict__ A,
                                             const float* __restrict__ Wm,
                                             float* __restrict__ C){
  __shared__ __align__(16) short Ah[BM * STR];
  __shared__ __align__(16) short Al[BM * STR];
  __shared__ __align__(16) short Bh[BN * STR];
  __shared__ __align__(16) short Bl[BN * STR];
  const int tid = threadIdx.x;
  const int m0 = blockIdx.y * BM, n0 = blockIdx.x * BN;
  const int lane = tid & 63, wid = tid >> 6;
  const int wm = (wid >> 1) * 64, wn = (wid & 1) * 64;
  const int cl = lane & 15, kg = lane >> 4;
  const int rr = tid >> 3, f4 = (tid & 7) * 4;
  f32x4 acc[4][4] = {};
  for (int k0 = 0; k0 < DIM; k0 += BK){
    #pragma unroll
    for (int i = 0; i < 4; ++i){
      const int r = rr + i * 32;
      f32x4 va = *reinterpret_cast<const f32x4*>(A  + (size_t)(m0 + r) * DIM + k0 + f4);
      f32x4 vb = *reinterpret_cast<const f32x4*>(Wm + (size_t)(n0 + r) * DIM + k0 + f4);
      s16x4 ha, la, hb, lb;
      #pragma unroll
      for (int j = 0; j < 4; ++j){
        ha[j] = f2bf(va[j]); la[j] = f2bf(va[j] - bf2f(ha[j]));
        hb[j] = f2bf(vb[j]); lb[j] = f2bf(vb[j] - bf2f(hb[j]));
      }
      *reinterpret_cast<s16x4*>(&Ah[r * STR + f4]) = ha;
      *reinterpret_cast<s16x4*>(&Al[r * STR + f4]) = la;
      *reinterpret_cast<s16x4*>(&Bh[r * STR + f4]) = hb;
      *reinterpret_cast<s16x4*>(&Bl[r * STR + f4]) = lb;
    }
    __syncthreads();
    s16x8 ah[4], al8[4], bh8[4], bl8[4];
    #pragma unroll
    for (int m = 0; m < 4; ++m){
      ah[m]  = *reinterpret_cast<const s16x8*>(&Ah[(wm + m * 16 + cl) * STR + kg * 8]);
      al8[m] = *reinterpret_cast<const s16x8*>(&Al[(wm + m * 16 + cl) * STR + kg * 8]);
    }
    #pragma unroll
    for (int n = 0; n < 4; ++n){
      bh8[n] = *reinterpret_cast<const s16x8*>(&Bh[(wn + n * 16 + cl) * STR + kg * 8]);
      bl8[n] = *reinterpret_cast<const s16x8*>(&Bl[(wn + n * 16 + cl) * STR + kg * 8]);
    }
    #pragma unroll
    for (int m = 0; m < 4; ++m)
      #pragma unroll
      for (int n = 0; n < 4; ++n){
        acc[m][n] = __builtin_amdgcn_mfma_f32_16x16x32_bf16(ah[m],  bh8[n], acc[m][n], 0, 0, 0);
        acc[m][n] = __builtin_amdgcn_mfma_f32_16x16x32_bf16(al8[m], bh8[n], acc[m][n], 0, 0, 0);
        acc[m][n] = __builtin_amdgcn_mfma_f32_16x16x32_bf16(ah[m],  bl8[n], acc[m][n], 0, 0, 0);
      }
    __syncthreads();
  }
  #pragma unroll
  for (int m = 0; m < 4; ++m){
    const int row = m0 + wm + m * 16 + kg * 4;
    #pragma unroll
    for (int n = 0; n < 4; ++n){
      const int col = n0 + wn + n * 16 + cl;
      #pragma unroll
      for (int j = 0; j < 4; ++j)
        C[(size_t)(row + j) * DIM + col] = acc[m][n][j];
    }
  }
}

__global__ __launch_bounds__(256) void k2_logits(const float* __restrict__ qp,
                                                 const float* __restrict__ keys,
                                                 float* __restrict__ out){
  __shared__ __align__(16) short Ah[BM * STR];
  __shared__ __align__(16) short Al[BM * STR];
  __shared__ __align__(16) short Bh[BN * STR];
  __shared__ __align__(16) short Bl[BN * STR];
  const int tid = threadIdx.x;
  const int b = blockIdx.z;
  const int t0 = blockIdx.y * BM, s0 = blockIdx.x * BN;
  const int lane = tid & 63, wid = tid >> 6;
  const int wm = (wid >> 1) * 64, wn = (wid & 1) * 64;
  const int cl = lane & 15, kg = lane >> 4;
  const int rr = tid >> 3, f4 = (tid & 7) * 4;
  f32x4 acc[4][4] = {};
  for (int k0 = 0; k0 < DIM; k0 += BK){
    #pragma unroll
    for (int i = 0; i < 4; ++i){
      const int r = rr + i * 32;
      f32x4 va = *reinterpret_cast<const f32x4*>(qp   + (size_t)((t0 + r) * NB + b) * DIM + k0 + f4);
      f32x4 vb = *reinterpret_cast<const f32x4*>(keys + ((size_t)b * DIM + s0 + r) * DIM + k0 + f4);
      s16x4 ha, la, hb, lb;
      #pragma unroll
      for (int j = 0; j < 4; ++j){
        ha[j] = f2bf(va[j]); la[j] = f2bf(va[j] - bf2f(ha[j]));
        hb[j] = f2bf(vb[j]); lb[j] = f2bf(vb[j] - bf2f(hb[j]));
      }
      *reinterpret_cast<s16x4*>(&Ah[r * STR + f4]) = ha;
      *reinterpret_cast<s16x4*>(&Al[r * STR + f4]) = la;
      *reinterpret_cast<s16x4*>(&Bh[r * STR + f4]) = hb;
      *reinterpret_cast<s16x4*>(&Bl[r * STR + f4]) = lb;
    }
    __syncthreads();
    s16x8 ah[4], al8[4], bh8[4], bl8[4];
    #pragma unroll
    for (int m = 0; m < 4; ++m){
      ah[m]  = *reinterpret_cast<const s16x8*>(&Ah[(wm + m * 16 + cl) * STR + kg * 8]);
      al8[m] = *reinterpret_cast<const s16x8*>(&Al[(wm + m * 16 + cl) * STR + kg * 8]);
    }
    #pragma unroll
    for (int n = 0; n < 4; ++n){
      bh8[n] = *reinterpret_cast<const s16x8*>(&Bh[(wn + n * 16 + cl) * STR + kg * 8]);
      bl8[n] = *reinterpret_cast<const s16x8*>(&Bl[(wn + n * 16 + cl) * STR + kg * 8]);
    }
    #pragma unroll
    for (int m = 0; m < 4; ++m)
      #pragma unroll
      for (int n = 0; n < 4; ++n){
        acc[m][n] = __builtin_amdgcn_mfma_f32_16x16x32_bf16(ah[m],  bh8[n], acc[m][n], 0, 0, 0);
        acc[m][n] = __builtin_amdgcn_mfma_f32_16x16x32_bf16(al8[m], bh8[n], acc[m][n], 0, 0, 0);
        acc[m][n] = __builtin_amdgcn_mfma_f32_16x16x32_bf16(ah[m],  bl8[n], acc[m][n], 0, 0, 0);
      }
    __syncthreads();
  }
  #pragma unroll
  for (int m = 0; m < 4; ++m){
    const int trow = t0 + wm + m * 16 + kg * 4;
    #pragma unroll
    for (int n = 0; n < 4; ++n){
      const int scol = s0 + wn + n * 16 + cl;
      #pragma unroll
      for (int j = 0; j < 4; ++j)
        out[((size_t)b * TQn + trow + j) * DIM + scol] = acc[m][n][j];
    }
  }
}

__global__ __launch_bounds__(256) void k4_ctx(const float* __restrict__ score,
                                              const float* __restrict__ values,
                                              float* __restrict__ ctx){
  __shared__ __align__(16) short As[BM * STR];
  __shared__ __align__(16) float Vs[BK * VSTR];
  const int tid = threadIdx.x;
  const int b = blockIdx.z;
  const int t0 = blockIdx.y * BM, v0 = blockIdx.x * BN;
  const int lane = tid & 63, wid = tid >> 6;
  const int wm = (wid >> 1) * 64, wn = (wid & 1) * 64;
  const int cl = lane & 15, kg = lane >> 4;
  const int rr = tid >> 3, f4 = (tid & 7) * 4;
  const int vr = tid >> 5, vc = tid & 31;
  f32x4 acc[4][4] = {};
  for (int k0 = 0; k0 < DIM; k0 += BK){
    #pragma unroll
    for (int i = 0; i < 4; ++i){
      const int r = rr + i * 32;
      f32x4 va = *reinterpret_cast<const f32x4*>(score + ((size_t)b * TQn + t0 + r) * DIM + k0 + f4);
      s16x4 ha;
      #pragma unroll
      for (int j = 0; j < 4; ++j) ha[j] = f2bf(va[j]);
      *reinterpret_cast<s16x4*>(&As[r * STR + f4]) = ha;
      const int vrow = vr + i * 8;
      f32x4 vv = *reinterpret_cast<const f32x4*>(values + ((size_t)b * DIM + k0 + vrow) * DIM + v0 + vc * 4);
      const int cb = vc ^ (((vrow >> 3) & 1) << 2);
      *reinterpret_cast<f32x4*>(&Vs[vrow * VSTR + cb * 4]) = vv;
    }
    __syncthreads();
    s16x8 af[4], bfr[4];
    #pragma unroll
    for (int m = 0; m < 4; ++m)
      af[m] = *reinterpret_cast<const s16x8*>(&As[(wm + m * 16 + cl) * STR + kg * 8]);
    #pragma unroll
    for (int n = 0; n < 4; ++n){
      const int colb = wn + n * 16 + cl;
      const int cb = (colb >> 2) ^ ((kg & 1) << 2);
      #pragma unroll
      for (int j = 0; j < 8; ++j){
        const int rowv = kg * 8 + j;
        bfr[n][j] = f2bf(Vs[rowv * VSTR + cb * 4 + (colb & 3)]);
      }
    }
    #pragma unroll
    for (int m = 0; m < 4; ++m)
      #pragma unroll
      for (int n = 0; n < 4; ++n)
        acc[m][n] = __builtin_amdgcn_mfma_f32_16x16x32_bf16(af[m], bfr[n], acc[m][n], 0, 0, 0);
    __syncthreads();
  }
  #pragma unroll
  for (int m = 0; m < 4; ++m){
    const int trow = t0 + wm + m * 16 + kg * 4;
    #pragma unroll
    for (int n = 0; n < 4; ++n){
      const int vcol = v0 + wn + n * 16 + cl;
      #pragma unroll
      for (int j = 0; j < 4; ++j)
        ctx[((size_t)b * TQn + trow + j) * DIM + vcol] = acc[m][n][j];
    }
  }
}

extern "C" void kernel_launch(void* const* d_in, const int* in_sizes, int n_in,
                              void* d_out, int out_size, void* d_ws, size_t ws_size,
                              hipStream_t stream){
  (void)in_sizes; (void)n_in; (void)out_size;
  const float* query  = (const float*)d_in[0];  // [1024][16][1024] == m-major [16384][1024]
  const float* keys   = (const float*)d_in[1];  // [16][1024][1024]
  const float* values = (const float*)d_in[2];  // [16][1024][1024]
  const float* mask   = (const float*)d_in[3];  // [16][1024]
  const float* Wm     = (const float*)d_in[4];  // [1024][1024]
  float* score = (float*)d_out;                              // [16][1024][1024]
  float* ctx   = score + (size_t)NB * TQn * DIM;             // qp-plane scratch then real ctx
  dim3 blk(256, 1, 1);
  dim3 blk512(512, 1, 1);

  const size_t M16 = (size_t)16 * 1024 * 1024;   // 16M shorts
  const size_t M1  = (size_t)1024 * 1024;
  const size_t need = (4 * M16 + 2 * M1 + 2 * M16) * 2;   // 196 MB
  if (ws_size >= need){
    short* w  = (short*)d_ws;
    short* qh = w;                 // query hi
    short* ql = qh + M16;
    short* kh = ql + M16;          // keys hi
    short* kl = kh + M16;
    short* wh = kl + M16;          // W hi
    short* wl = wh + M1;
    short* vT = wl + M1;           // values^T bf16 [b][v][s]
    short* sb = vT + M16;          // score bf16
    short* qph = (short*)ctx;      // qp hi plane (m-major [16384][1024])
    short* qpl = qph + M16;

    k0_split<<<dim3(16384, 1, 1), blk, 0, stream>>>(query, qh, ql);
    k0_split<<<dim3(16384, 1, 1), blk, 0, stream>>>(keys, kh, kl);
    k0_split<<<dim3(1024, 1, 1), blk, 0, stream>>>(Wm, wh, wl);
    k0_vtrans<<<dim3(16, 16, 16), blk, 0, stream>>>(values, vT);
    // K1: qp = query . W^T -> bf16 hi/lo planes (M=16384, N=1024)
    gemm256<3, 1><<<dim3(4, 64, 1), blk512, 0, stream>>>(qh, ql, wh, wl,
        nullptr, qph, qpl, 1, 0, 1, 0, 0);
    // K2: logits[b][t][s] = qp[t*16+b][:] . keys[b][s][:]
    gemm256<3, 0><<<dim3(4, 4, 16), blk512, 0, stream>>>(qph, qpl, kh, kl,
        score, nullptr, nullptr, 16, 1, 1, 1024, 1024);
    k3_softmax<<<dim3(NB * TQn, 1, 1), blk, 0, stream>>>(score, mask, sb);
    // K4: ctx[b][t][v] = score[b][t][:] . vT[b][v][:]
    gemm256<1, 0><<<dim3(4, 4, 16), blk512, 0, stream>>>(sb, nullptr, vT, nullptr,
        ctx, nullptr, nullptr, 1, 1024, 1, 1024, 1024);
  } else {
    k1_qp<<<dim3(DIM / BN, (TQn * NB) / BM, 1), blk, 0, stream>>>(query, Wm, ctx);
    k2_logits<<<dim3(DIM / BN, TQn / BM, NB), blk, 0, stream>>>(ctx, keys, score);
    k3_softmax<<<dim3(NB * TQn, 1, 1), blk, 0, stream>>>(score, mask, nullptr);
    k4_ctx<<<dim3(DIM / BN, TQn / BM, NB), blk, 0, stream>>>(score, values, ctx);
  }
}